// Round 1
// baseline (1247.619 us; speedup 1.0000x reference)
//
#include <hip/hip_runtime.h>

// Reference math: dt = |i-j|, dx = 0, s^2 = -dt^2 + dx^2 = -dt^2 <= 0.
// The spacelike mask (s^2 > 0) is identically False, so
//   penalty = sum(attn^2 * 0) = 0
//   total_loss = base_loss + LAMBDA_REG * (0 / L) = base_loss   (bit-exact:
//   base_loss + 0.01f*0.0f == base_loss in IEEE fp32)
// The [L,B,H,S,S] attention tensor never needs to be read. The whole op is
// a single-float copy: d_out[0] = base_loss.

__global__ void spacetime_reg_copy_base_loss(const float* __restrict__ base_loss,
                                             float* __restrict__ out) {
    out[0] = base_loss[0];
}

extern "C" void kernel_launch(void* const* d_in, const int* in_sizes, int n_in,
                              void* d_out, int out_size, void* d_ws, size_t ws_size,
                              hipStream_t stream) {
    // in order of setup_inputs(): d_in[0] = attn_weights [12,2,12,1024,1024] f32,
    //                             d_in[1] = base_loss scalar f32
    const float* base_loss = (const float*)d_in[1];
    float* out = (float*)d_out;
    spacetime_reg_copy_base_loss<<<1, 1, 0, stream>>>(base_loss, out);
}